// Round 18
// baseline (1464.680 us; speedup 1.0000x reference)
//
#include <hip/hip_runtime.h>

typedef __attribute__((ext_vector_type(4))) float f32x4;
typedef __attribute__((ext_vector_type(2))) float f32x2;
typedef __attribute__((ext_vector_type(8))) short s16x8;
typedef __attribute__((ext_vector_type(4))) short s16x4;

#define B_ 64
#define S_ 128
#define T_ 32
#define H_ 512
#define V_ 32000
#define NTILES 2000  // 16 M-blocks(128 rows) * 125 col-tiles(256)

// sync layout: tile counter, 64 phase slots, aggregated step counter.
#define SY_TILE 32
#define SY_SLOT 64   // slots[0..63] at dwords 64..127
#define SY_DONE 192  // completed-steps counter (own line)

__device__ __forceinline__ unsigned short f2bf(float f) {
  union { float f; unsigned u; } x; x.f = f;
  unsigned r = x.u + 0x7FFFu + ((x.u >> 16) & 1u);
  return (unsigned short)(r >> 16);
}
__device__ __forceinline__ float bf2f(unsigned short u) {
  union { unsigned u; float f; } x; x.u = ((unsigned)u) << 16; return x.f;
}
__device__ __forceinline__ float fast_tanh(float x) {
  float e = __expf(2.0f * x);
  return 1.0f - 2.0f / (e + 1.0f);
}
__device__ __forceinline__ float fast_sig(float x) {
  return 1.0f / (1.0f + __expf(-x));
}
__device__ __forceinline__ void gload16(const void* g, void* l) {
  __builtin_amdgcn_global_load_lds(
      (const __attribute__((address_space(1))) void*)g,
      (__attribute__((address_space(3))) void*)l, 16, 0, 0);
}
__device__ __forceinline__ void gload16nt(const void* g, void* l) {
  __builtin_amdgcn_global_load_lds(
      (const __attribute__((address_space(1))) void*)g,
      (__attribute__((address_space(3))) void*)l, 16, 0, 2);
}

// coherent dword ops (bypass L1/L2, write-through) — no fences anywhere.
__device__ __forceinline__ unsigned ald(const unsigned* p) {
  return __hip_atomic_load(p, __ATOMIC_RELAXED, __HIP_MEMORY_SCOPE_AGENT);
}
__device__ __forceinline__ void ast(unsigned* p, unsigned v) {
  __hip_atomic_store(p, v, __ATOMIC_RELAXED, __HIP_MEMORY_SCOPE_AGENT);
}
__device__ __forceinline__ float aldf(const float* p) {
  union { unsigned u; float f; } x; x.u = ald((const unsigned*)p); return x.f;
}
__device__ __forceinline__ void astf(float* p, float v) {
  union { unsigned u; float f; } x; x.f = v; ast((unsigned*)p, x.u);
}

// Slot barrier (R12-proven): RELAXED arrival store (release emits buffer_wbl2,
// ~2.5µs/barrier); __syncthreads drains vmcnt first; data is write-through.
__device__ __forceinline__ void phase_sync(unsigned* sync, int bid,
                                           unsigned st_ph, int nmask,
                                           unsigned wt_ph) {
  __syncthreads();
  if (threadIdx.x == 0)
    __hip_atomic_store(&sync[SY_SLOT + bid], st_ph, __ATOMIC_RELAXED,
                       __HIP_MEMORY_SCOPE_AGENT);
  if (threadIdx.x < 64) {
    const unsigned* p = &sync[SY_SLOT + (threadIdx.x & nmask)];
    while (ald(p) < wt_ph) __builtin_amdgcn_s_sleep(1);
  }
  __syncthreads();
}

// ---------------------------------------------------------------------------
// Prep GEMM: C[Mv,N] = A[.,K]bf16(lda) @ W[N,K]bf16^T + bias; 128x128, BK=32.
// ---------------------------------------------------------------------------
template <int OUTBF>
__global__ __launch_bounds__(256) void big_gemm_k(
    const unsigned short* __restrict__ A, int lda,
    const unsigned short* __restrict__ W, const float* __restrict__ bias,
    void* __restrict__ Cv, int Mv, int N, int K) {
  __shared__ unsigned short As[128 * 32];
  __shared__ unsigned short Bs[128 * 32];
  const int t = threadIdx.x;
  const int wave = t >> 6, lane = t & 63;
  const int m0 = blockIdx.x * 128, n0 = blockIdx.y * 128;
  const int wm = (wave & 1) * 64, wn = (wave >> 1) * 64;
  const int fr = lane & 15, fq = lane >> 4;

  f32x4 acc[4][4];
#pragma unroll
  for (int i = 0; i < 4; ++i)
#pragma unroll
    for (int j = 0; j < 4; ++j) acc[i][j] = (f32x4){0.f, 0.f, 0.f, 0.f};

  const int g = (((lane & 3) ^ ((lane >> 3) & 3))) * 8;
  const size_t a_g0 = (size_t)(m0 + wave * 32 + (lane >> 2)) * lda + g;
  const size_t b_g0 = (size_t)(n0 + wave * 32 + (lane >> 2)) * K + g;
  unsigned short* As_w = As + wave * 1024;
  unsigned short* Bs_w = Bs + wave * 1024;
  const int sl = (fq ^ ((fr >> 1) & 3)) * 8;

  for (int kk = 0; kk < K; kk += 32) {
    gload16(A + a_g0 + kk, As_w);
    gload16(A + a_g0 + (size_t)16 * lda + kk, As_w + 512);
    gload16(W + b_g0 + kk, Bs_w);
    gload16(W + b_g0 + (size_t)16 * K + kk, Bs_w + 512);
    __syncthreads();
    s16x8 af[4], bfr[4];
#pragma unroll
    for (int f = 0; f < 4; ++f) {
      af[f] = *(const s16x8*)(As + (wm + f * 16 + fr) * 32 + sl);
      bfr[f] = *(const s16x8*)(Bs + (wn + f * 16 + fr) * 32 + sl);
    }
#pragma unroll
    for (int fm = 0; fm < 4; ++fm)
#pragma unroll
      for (int fn = 0; fn < 4; ++fn)
        acc[fm][fn] = __builtin_amdgcn_mfma_f32_16x16x32_bf16(af[fm], bfr[fn],
                                                              acc[fm][fn], 0, 0, 0);
    __syncthreads();
  }

#pragma unroll
  for (int fn = 0; fn < 4; ++fn) {
    int col = n0 + wn + fn * 16 + fr;
    float bv = bias[col];
#pragma unroll
    for (int fm = 0; fm < 4; ++fm) {
      int rb = m0 + wm + fm * 16 + fq * 4;
#pragma unroll
      for (int i = 0; i < 4; ++i) {
        int r = rb + i;
        if (r < Mv) {
          if (OUTBF)
            ((unsigned short*)Cv)[(size_t)r * N + col] = f2bf(acc[fm][fn][i] + bv);
          else
            ((float*)Cv)[(size_t)r * N + col] = acc[fm][fn][i] + bv;
        }
      }
    }
  }
}

// ---------------------------------------------------------------------------
// Fused persistent kernel: 256 blocks x 512 threads (1 block/CU).
// R17 structure + SPLIT-K P3: pair (j, j+32) each does K=512 half of the
// gi_w GEMM (8 dbuf iters instead of 16); j+32 publishes f32 partials to
// gpart[j] + slot=ph+3 early; j adds partial + gix, runs GRU.
// Block 0 publishes SY_DONE=step+1 after each step's final barrier.
// ---------------------------------------------------------------------------
__global__ __launch_bounds__(512) void fused_k(
    float* __restrict__ h, unsigned short* __restrict__ hbf_step,
    float* __restrict__ hgh_step, const unsigned short* __restrict__ Wcomb,
    const unsigned short* __restrict__ encp_bf,
    const unsigned short* __restrict__ enc_bf, const float* __restrict__ v,
    const int* __restrict__ src_tok, const unsigned short* __restrict__ Ww,
    const unsigned short* __restrict__ gix, const float* __restrict__ b_hh,
    unsigned short* __restrict__ Abf, const unsigned short* __restrict__ outW,
    const float* __restrict__ out_b, float* __restrict__ out,
    float* __restrict__ gpart, unsigned* __restrict__ sync) {
  __shared__ __align__(16) char smem[65536];
  const int t = threadIdx.x;
  const int lane = t & 63, w = t >> 6;
  const int fr = lane & 15, fq = lane >> 4;

  if (blockIdx.x < 64) {
    // ================= producer =================
    unsigned short* A0 = (unsigned short*)smem;            // [64][72] 9216
    unsigned short* A1 = (unsigned short*)(smem + 9216);   // [64][72]
    unsigned short* W0 = (unsigned short*)(smem + 18432);  // [48][72] 6912
    unsigned short* W1 = (unsigned short*)(smem + 25344);  // [48][72]
    unsigned short* Wp1 = (unsigned short*)(smem + 32256); // [32][520] 33280 (exclusive)
    float* gsm = (float*)smem;                             // [64][48] alias A0/A1
    float* sc = (float*)(smem + 12288);                    // [132]  alias A1
    const int j = blockIdx.x;
    const int jj = j & 31, half = j >> 5;
    const int ar = t >> 3, ak = (t & 7) * 8;
    const int p1_n0 = j * 32;
    const int rowt_p1 = w & 3, colt_p1 = w >> 2;
    const int rowt = (w < 4) ? w : (w - 4);

    // persistent P1 weight slice: Wcomb rows p1_n0..+32, K=512 (cached)
#pragma unroll
    for (int c = 0; c < 4; ++c) {
      int id = t * 4 + c;
      int r = id >> 6, cc = id & 63;
      s16x8 wv = *(const s16x8*)(Wcomb + (size_t)(p1_n0 + r) * 512 + cc * 8);
      *(s16x8*)(Wp1 + r * 520 + cc * 8) = wv;
    }

    // persistent P3 weight chunks in registers: this block's K-half.
    const int wgate = ar >> 4, wdr = ar & 15;
    const int d0 = jj * 16;
    const unsigned short* wwrow =
        Ww + (size_t)(wgate * 512 + d0 + wdr) * 1024 + ak + half * 512;
    s16x8 pwreg[8];
    if (t < 384) {
#pragma unroll
      for (int p = 0; p < 8; ++p) pwreg[p] = *(const s16x8*)(wwrow + p * 64);
    }
    float* gp = gpart + (size_t)jj * 3072;  // [64][48] f32 partial
    __syncthreads();

    for (int step = 0; step < 31; ++step) {
      const unsigned short* hbfS = hbf_step + (size_t)step * 64 * 512;
      unsigned short* hbfS1 = hbf_step + (size_t)(step + 1) * 64 * 512;
      float* hghS = hgh_step + (size_t)step * 64 * 2048;
      const unsigned ph = 3u * step;

      // ---------------- P1: hghS = hbfS @ Wcomb^T (dbuf, 1 sync/iter) ------
      {
        s16x8 pa[8];
#pragma unroll
        for (int p = 0; p < 8; ++p)
          pa[p] = *(const s16x8*)(hbfS + ar * 512 + p * 64 + ak);
        *(s16x8*)(A0 + ar * 72 + ak) = pa[0];
        __syncthreads();
        f32x4 acc = {0.f, 0.f, 0.f, 0.f};
#pragma unroll
        for (int it = 0; it < 8; ++it) {
          unsigned short* bufR = (it & 1) ? A1 : A0;
          unsigned short* bufW = (it & 1) ? A0 : A1;
          s16x8 a0 = *(const s16x8*)(bufR + (rowt_p1 * 16 + fr) * 72 + fq * 8);
          s16x8 a1 =
              *(const s16x8*)(bufR + (rowt_p1 * 16 + fr) * 72 + 32 + fq * 8);
          if (it < 7) *(s16x8*)(bufW + ar * 72 + ak) = pa[it + 1];
          s16x8 b0 =
              *(const s16x8*)(Wp1 + (colt_p1 * 16 + fr) * 520 + it * 64 + fq * 8);
          s16x8 b1 = *(const s16x8*)(Wp1 + (colt_p1 * 16 + fr) * 520 + it * 64 +
                                     32 + fq * 8);
          acc = __builtin_amdgcn_mfma_f32_16x16x32_bf16(a0, b0, acc, 0, 0, 0);
          acc = __builtin_amdgcn_mfma_f32_16x16x32_bf16(a1, b1, acc, 0, 0, 0);
          __syncthreads();
        }
        int col = p1_n0 + colt_p1 * 16 + fr;
#pragma unroll
        for (int i = 0; i < 4; ++i)
          astf(&hghS[(rowt_p1 * 16 + fq * 4 + i) * 2048 + col], acc[i]);
      }
      phase_sync(sync, j, ph + 1, 15, ph + 1);  // wait hproj (blocks 0..15)

      // ---------------- P2: attention for b = j ----------------
      {
        const int b = j;
        const float* hp = hghS + (size_t)b * 2048;
        float vh[8], hh[8];
        {
          f32x4 v0 = *(const f32x4*)(v + lane * 8);
          f32x4 v1 = *(const f32x4*)(v + lane * 8 + 4);
          f32x4 h0 = *(const f32x4*)(hp + lane * 8);
          f32x4 h1 = *(const f32x4*)(hp + lane * 8 + 4);
#pragma unroll
          for (int q = 0; q < 4; ++q) {
            vh[q] = v0[q]; vh[4 + q] = v1[q];
            hh[q] = h0[q]; hh[4 + q] = h1[q];
          }
        }
        for (int s = w * 16; s < w * 16 + 16; ++s) {
          s16x8 e =
              *(const s16x8*)(encp_bf + (size_t)(b * 128 + s) * 512 + lane * 8);
          float p = 0.f;
#pragma unroll
          for (int q = 0; q < 8; ++q)
            p += vh[q] * fast_tanh(hh[q] + bf2f((unsigned short)e[q]));
          for (int m = 32; m; m >>= 1) p += __shfl_xor(p, m);
          if (lane == 0)
            sc[s] = (src_tok[b * 128 + s] != 0) ? p : -__builtin_inff();
        }
        __syncthreads();
        if (t < 64) {
          float a0 = sc[t], a1 = sc[t + 64];
          float mx = fmaxf(a0, a1);
          for (int m = 32; m; m >>= 1) mx = fmaxf(mx, __shfl_xor(mx, m));
          float e0 = __expf(a0 - mx), e1 = __expf(a1 - mx);
          float ssum = e0 + e1;
          for (int m = 32; m; m >>= 1) ssum += __shfl_xor(ssum, m);
          float inv = 1.0f / ssum;
          sc[t] = e0 * inv;
          sc[t + 64] = e1 * inv;
        }
        __syncthreads();
        const int d = t * 2;
        float w0 = 0.f, w1 = 0.f;
#pragma unroll 16
        for (int s = 0; s < 128; ++s) {
          float a = sc[s];
          unsigned u = *(const unsigned*)(enc_bf + (size_t)(b * 128 + s) * 1024 + d);
          union { unsigned u; float f; } lo, hi;
          lo.u = u << 16; hi.u = u & 0xffff0000u;
          w0 += a * lo.f; w1 += a * hi.f;
        }
        unsigned pk = ((unsigned)f2bf(w1) << 16) | (unsigned)f2bf(w0);
        ast((unsigned*)(Abf + (size_t)(step * 64 + b) * 2048 + 512 + d), pk);
      }
      phase_sync(sync, j, ph + 2, 63, ph + 2);  // wait all: weighted + gates

      // ------------- P3 split-K + GRU: pair (jj, jj+32) -------------
      {
        const int r0 = step * 64;
        const unsigned short* abrow =
            Abf + (size_t)(r0 + ar) * 2048 + 512 + half * 512 + ak;
        s16x8 pa[8];
#pragma unroll
        for (int p = 0; p < 8; ++p) pa[p] = *(const s16x8*)(abrow + p * 64);
        *(s16x8*)(A0 + ar * 72 + ak) = pa[0];
        if (t < 384) *(s16x8*)(W0 + ar * 72 + ak) = pwreg[0];
        __syncthreads();
        f32x4 acc0 = {0.f, 0.f, 0.f, 0.f}, acc1 = {0.f, 0.f, 0.f, 0.f};
#pragma unroll
        for (int it = 0; it < 8; ++it) {
          unsigned short* aR = (it & 1) ? A1 : A0;
          unsigned short* wR = (it & 1) ? W1 : W0;
          unsigned short* aW = (it & 1) ? A0 : A1;
          unsigned short* wW = (it & 1) ? W0 : W1;
          s16x8 a0 = *(const s16x8*)(aR + (rowt * 16 + fr) * 72 + fq * 8);
          s16x8 a1 = *(const s16x8*)(aR + (rowt * 16 + fr) * 72 + 32 + fq * 8);
          if (it < 7) {
            *(s16x8*)(aW + ar * 72 + ak) = pa[it + 1];
            if (t < 384) *(s16x8*)(wW + ar * 72 + ak) = pwreg[it + 1];
          }
          if (w < 4) {
            s16x8 b0 = *(const s16x8*)(wR + fr * 72 + fq * 8);
            s16x8 b1 = *(const s16x8*)(wR + fr * 72 + 32 + fq * 8);
            s16x8 c0 = *(const s16x8*)(wR + (32 + fr) * 72 + fq * 8);
            s16x8 c1 = *(const s16x8*)(wR + (32 + fr) * 72 + 32 + fq * 8);
            acc0 = __builtin_amdgcn_mfma_f32_16x16x32_bf16(a0, b0, acc0, 0, 0, 0);
            acc0 = __builtin_amdgcn_mfma_f32_16x16x32_bf16(a1, b1, acc0, 0, 0, 0);
            acc1 = __builtin_amdgcn_mfma_f32_16x16x32_bf16(a0, c0, acc1, 0, 0, 0);
            acc1 = __builtin_amdgcn_mfma_f32_16x16x32_bf16(a1, c1, acc1, 0, 0, 0);
          } else {
            s16x8 b0 = *(const s16x8*)(wR + (16 + fr) * 72 + fq * 8);
            s16x8 b1 = *(const s16x8*)(wR + (16 + fr) * 72 + 32 + fq * 8);
            acc0 = __builtin_amdgcn_mfma_f32_16x16x32_bf16(a0, b0, acc0, 0, 0, 0);
            acc0 = __builtin_amdgcn_mfma_f32_16x16x32_bf16(a1, b1, acc0, 0, 0, 0);
          }
          __syncthreads();
        }
        const int colt0 = (w < 4) ? 0 : 1;
        if (half) {
          // publish K-hi partial fragments (write-through), slot in phase_sync
#pragma unroll
          for (int i = 0; i < 4; ++i) {
            int row = rowt * 16 + fq * 4 + i;
            astf(&gp[row * 48 + colt0 * 16 + fr], acc0[i]);
          }
          if (w < 4) {
#pragma unroll
            for (int i = 0; i < 4; ++i) {
              int row = rowt * 16 + fq * 4 + i;
              astf(&gp[row * 48 + 32 + fr], acc1[i]);
            }
          }
        } else {
          // wait partner partial (published with its slot=ph+3)
          if (t == 0) {
            while (ald(&sync[SY_SLOT + jj + 32]) < ph + 3)
              __builtin_amdgcn_s_sleep(1);
          }
          __syncthreads();
#pragma unroll
          for (int i = 0; i < 4; ++i) {
            int row = rowt * 16 + fq * 4 + i;
            float part = aldf(&gp[row * 48 + colt0 * 16 + fr]);
            gsm[row * 48 + colt0 * 16 + fr] =
                acc0[i] + part +
                bf2f(gix[(size_t)(r0 + row) * 1536 + colt0 * 512 + d0 + fr]);
          }
          if (w < 4) {
#pragma unroll
            for (int i = 0; i < 4; ++i) {
              int row = rowt * 16 + fq * 4 + i;
              float part = aldf(&gp[row * 48 + 32 + fr]);
              gsm[row * 48 + 32 + fr] =
                  acc1[i] + part +
                  bf2f(gix[(size_t)(r0 + row) * 1536 + 1024 + d0 + fr]);
            }
          }
          __syncthreads();
          {
            int e = t * 2;
            int b = e >> 4, dd = e & 15, d = d0 + dd;
            float hv2[2];
            unsigned short hb2[2];
#pragma unroll
            for (int k = 0; k < 2; ++k) {
              float ir = gsm[b * 48 + dd + k];
              float iz = gsm[b * 48 + 16 + dd + k];
              float inn = gsm[b * 48 + 32 + dd + k];
              float hr = hghS[b * 2048 + 512 + d + k] + b_hh[d + k];
              float hz = hghS[b * 2048 + 1024 + d + k] + b_hh[512 + d + k];
              float hn = hghS[b * 2048 + 1536 + d + k] + b_hh[1024 + d + k];
              float r = fast_sig(ir + hr);
              float z = fast_sig(iz + hz);
              float n = fast_tanh(inn + r * hn);
              hv2[k] = (1.0f - z) * n + z * h[b * 512 + d + k];
              hb2[k] = f2bf(hv2[k]);
            }
            h[b * 512 + d] = hv2[0];  // producer-block-local across steps
            h[b * 512 + d + 1] = hv2[1];
            unsigned pk = ((unsigned)hb2[1] << 16) | (unsigned)hb2[0];
            ast((unsigned*)(hbfS1 + b * 512 + d), pk);
            ast((unsigned*)(Abf + (size_t)(r0 + b) * 2048 + d), pk);
          }
        }
      }
      phase_sync(sync, j, ph + 3, 31, ph + 3);  // wait hbf writers (0..31)
      // Block 0 has now observed slots 0..31 >= ph+3 -> step complete.
      if (j == 0 && t == 0) ast(&sync[SY_DONE], (unsigned)(step + 1));
    }
  }

  // ================= worker (all blocks; producers join when done) ==========
  unsigned short* As2 = (unsigned short*)smem;            // [128][64] swizzled
  unsigned short* Bs2 = (unsigned short*)(smem + 16384);  // [256][64] swizzled
  unsigned* shp = (unsigned*)(smem + 65532);              // sh_idx (alias)
  const int wr = (w >> 2) * 64, wc = (w & 3) * 64;

  int rowA[2], cgA[2], rowB[4], cgB[4];
#pragma unroll
  for (int c = 0; c < 2; ++c) {
    int id = (w * 2 + c) * 64 + lane;
    rowA[c] = id >> 3;
    cgA[c] = ((id & 7) - rowA[c]) & 7;
  }
#pragma unroll
  for (int c = 0; c < 4; ++c) {
    int id = (w * 4 + c) * 64 + lane;
    rowB[c] = id >> 3;
    cgB[c] = ((id & 7) - rowB[c]) & 7;
  }

  for (;;) {
    __syncthreads();
    if (t == 0)
      *shp = __hip_atomic_fetch_add(&sync[SY_TILE], 1u, __ATOMIC_RELAXED,
                                    __HIP_MEMORY_SCOPE_AGENT);
    __syncthreads();
    unsigned idx = *shp;
    if (idx >= NTILES) break;
    int mb = idx / 125;
    int nt = idx - mb * 125;
    int gate = mb * 2 + 1;
    if (gate > 30) gate = 30;
    unsigned need = (unsigned)gate + 1u;  // steps completed
    if (t == 0) {
      while (ald(&sync[SY_DONE]) < need) __builtin_amdgcn_s_sleep(32);
    }
    __syncthreads();

    const int m0 = mb * 128, n0 = nt * 256;
    f32x4 acc[4][4];
#pragma unroll
    for (int i = 0; i < 4; ++i)
#pragma unroll
      for (int jj2 = 0; jj2 < 4; ++jj2) acc[i][jj2] = (f32x4){0.f, 0.f, 0.f, 0.f};

    for (int kk = 0; kk < 2048; kk += 64) {
#pragma unroll
      for (int c = 0; c < 2; ++c)
        gload16(Abf + (size_t)(m0 + rowA[c]) * 2048 + kk + cgA[c] * 8,
                As2 + (w * 2 + c) * 512);
#pragma unroll
      for (int c = 0; c < 4; ++c)
        gload16nt(outW + (size_t)(n0 + rowB[c]) * 2048 + kk + cgB[c] * 8,
                  Bs2 + (w * 4 + c) * 512);
      __syncthreads();
#pragma unroll
      for (int kh = 0; kh < 2; ++kh) {
        int cg = kh * 4 + fq;
        s16x8 af[4], bf_[4];
#pragma unroll
        for (int i = 0; i < 4; ++i) {
          int rr = wr + i * 16 + fr;
          af[i] = *(const s16x8*)(As2 + rr * 64 + (((cg + rr) & 7) * 8));
        }
#pragma unroll
        for (int jj2 = 0; jj2 < 4; ++jj2) {
          int rr = wc + jj2 * 16 + fr;
          bf_[jj2] = *(const s16x8*)(Bs2 + rr * 64 + (((cg + rr) & 7) * 8));
        }
#pragma unroll
        for (int i = 0; i < 4; ++i)
#pragma unroll
          for (int jj2 = 0; jj2 < 4; ++jj2)
            acc[i][jj2] = __builtin_amdgcn_mfma_f32_16x16x32_bf16(
                af[i], bf_[jj2], acc[i][jj2], 0, 0, 0);
      }
      __syncthreads();
    }

#pragma unroll
    for (int jj2 = 0; jj2 < 4; ++jj2) {
      int col = n0 + wc + jj2 * 16 + fr;
      float bv = out_b[col];
#pragma unroll
      for (int i = 0; i < 4; ++i) {
        int rb = m0 + wr + i * 16 + fq * 4;
#pragma unroll
        for (int ii = 0; ii < 4; ++ii) {
          int r = rb + ii;
          if (r < 1984) out[(size_t)(r + 64) * V_ + col] = acc[i][jj2][ii] + bv;
        }
      }
    }
  }
}

// ---------------------------------------------------------------------------
// Prep kernels
// ---------------------------------------------------------------------------
__global__ __launch_bounds__(256) void cast_bf16_k(const float* __restrict__ src,
                                                   unsigned short* __restrict__ dst,
                                                   int n4) {
  int i = blockIdx.x * 256 + threadIdx.x;
  if (i >= n4) return;
  f32x4 f = *(const f32x4*)(src + (size_t)i * 4);
  s16x4 o;
#pragma unroll
  for (int q = 0; q < 4; ++q) o[q] = (short)f2bf(f[q]);
  *(s16x4*)(dst + (size_t)i * 4) = o;
}

__global__ __launch_bounds__(256) void enc_cast_k(const float* __restrict__ enc,
                                                  unsigned short* __restrict__ dst) {
  int i = blockIdx.x * 256 + threadIdx.x;
  int n = i * 4;
  int row = n >> 10, d = n & 1023;
  int s = row & (S_ - 1), b = row >> 7;
  f32x4 f = *(const f32x4*)(enc + ((size_t)s * B_ + b) * 1024 + d);
  s16x4 o;
#pragma unroll
  for (int q = 0; q < 4; ++q) o[q] = (short)f2bf(f[q]);
  *(s16x4*)(dst + (size_t)row * 1024 + d) = o;
}

__global__ __launch_bounds__(256) void build_wcomb_k(const float* __restrict__ aW,
                                                     const float* __restrict__ whh,
                                                     unsigned short* __restrict__ dst) {
  int idx = (blockIdx.x * 256 + threadIdx.x) * 4;
  int n = idx >> 9, k = idx & 511;
  const float* src = (n < 512) ? (aW + (size_t)n * 1536 + k)
                               : (whh + (size_t)(n - 512) * 512 + k);
  f32x4 f = *(const f32x4*)src;
  s16x4 o;
#pragma unroll
  for (int q = 0; q < 4; ++q) o[q] = (short)f2bf(f[q]);
  *(s16x4*)(dst + idx) = o;
}

__global__ __launch_bounds__(256) void build_wenc_k(const float* __restrict__ aW,
                                                    unsigned short* __restrict__ dst) {
  int idx = (blockIdx.x * 256 + threadIdx.x) * 4;
  int n = idx >> 10, k = idx & 1023;
  f32x4 f = *(const f32x4*)(aW + (size_t)n * 1536 + 512 + k);
  s16x4 o;
#pragma unroll
  for (int q = 0; q < 4; ++q) o[q] = (short)f2bf(f[q]);
  *(s16x4*)(dst + idx) = o;
}

__global__ __launch_bounds__(256) void build_wxw_k(const float* __restrict__ wih,
                                                   unsigned short* __restrict__ wx,
                                                   unsigned short* __restrict__ ww) {
  int flat = blockIdx.x * 256 + threadIdx.x;  // over 1536*384
  int n = flat / 384, c4 = (flat % 384) * 4;
  f32x4 f = *(const f32x4*)(wih + (size_t)n * 1536 + c4);
  s16x4 o;
#pragma unroll
  for (int q = 0; q < 4; ++q) o[q] = (short)f2bf(f[q]);
  if (c4 < 512)
    *(s16x4*)(wx + (size_t)n * 512 + c4) = o;
  else
    *(s16x4*)(ww + (size_t)n * 1024 + (c4 - 512)) = o;
}

__global__ __launch_bounds__(256) void hcast_k(const float* __restrict__ hidden,
                                               unsigned short* __restrict__ hbf0) {
  int i = blockIdx.x * 256 + threadIdx.x;
  f32x2 f = *(const f32x2*)(hidden + (size_t)i * 2);
  unsigned pk = ((unsigned)f2bf(f[1]) << 16) | (unsigned)f2bf(f[0]);
  *(unsigned*)(hbf0 + (size_t)i * 2) = pk;
}

__global__ __launch_bounds__(256) void xgather_k(const int* __restrict__ trg,
                                                 const float* __restrict__ embed,
                                                 unsigned short* __restrict__ Abf) {
  int row = blockIdx.x;  // 0..1983
  int tt = row >> 6, b = row & 63;
  int tok = trg[b * T_ + tt];
  int d = threadIdx.x * 2;
  unsigned pk = 0;
  if (tok != 0) {
    f32x2 f = *(const f32x2*)(embed + (size_t)tok * H_ + d);
    pk = ((unsigned)f2bf(f[1]) << 16) | (unsigned)f2bf(f[0]);
  }
  *(unsigned*)(Abf + (size_t)row * 2048 + 1536 + d) = pk;
}

extern "C" void kernel_launch(void* const* d_in, const int* in_sizes, int n_in,
                              void* d_out, int out_size, void* d_ws, size_t ws_size,
                              hipStream_t stream) {
  const int* trg = (const int*)d_in[0];
  const int* srt = (const int*)d_in[1];
  const float* enc = (const float*)d_in[2];
  const float* hidden = (const float*)d_in[3];
  const float* embed = (const float*)d_in[4];
  const float* attn_W = (const float*)d_in[5];
  const float* attn_b = (const float*)d_in[6];
  const float* vv = (const float*)d_in[7];
  const float* W_ih = (const float*)d_in[8];
  const float* W_hh = (const float*)d_in[9];
  const float* b_ih = (const float*)d_in[10];
  const float* b_hh = (const float*)d_in[11];
  const float* out_W = (const float*)d_in[12];
  const float* out_b = (const float*)d_in[13];
  float* out = (float*)d_out;

  char* ws = (char*)d_ws;
  size_t off = 0;
  auto alloc = [&](size_t bytes) {
    size_t o = off;
    off += (bytes + 255) & ~(size_t)255;
    return ws + o;
  };

  unsigned short* outW_bf = (unsigned short*)alloc((size_t)V_ * 2048 * 2);
  unsigned short* Abf = (unsigned short*)alloc((size_t)2048 * 2048 * 2);
  unsigned short* enc_bf = (unsigned short*)alloc((size_t)B_ * S_ * 1024 * 2);
  unsigned short* encp_bf = (unsigned short*)alloc((size_t)B_ * S_ * 512 * 2);
  unsigned short* gix_bf = (unsigned short*)alloc((size_t)1984 * 1536 * 2);
  unsigned short* Wcomb = (unsigned short*)alloc((size_t)2048 * 512 * 2);
  unsigned short* Wenc = (unsigned short*)alloc((size_t)512 * 1024 * 2);
  unsigned short* Wx = (unsigned short*)alloc((size_t)1536 * 512 * 2);
  unsigned short* Ww = (unsigned short*)alloc((size_t)1536 * 1024 * 2);
  float* hgh_step = (float*)alloc((size_t)31 * B_ * 2048 * 4);  // 16.25 MB
  unsigned short* hbf_step = (unsigned short*)alloc((size_t)32 * B_ * H_ * 2);
  float* h = (float*)alloc((size_t)B_ * H_ * 4);
  float* gpart = (float*)alloc((size_t)32 * 3072 * 4);  // 384 KB
  unsigned* syncb = (unsigned*)alloc(8192);

  hipMemsetAsync(out, 0, (size_t)B_ * V_ * 4, stream);
  hipMemsetAsync(syncb, 0, 8192, stream);
  hipMemsetAsync(Abf + (size_t)1984 * 2048, 0, (size_t)64 * 2048 * 2, stream);
  hipMemcpyAsync(h, hidden, (size_t)B_ * H_ * 4, hipMemcpyDeviceToDevice, stream);

  cast_bf16_k<<<(V_ * 2048 / 4 + 255) / 256, 256, 0, stream>>>(out_W, outW_bf,
                                                               V_ * 2048 / 4);
  build_wcomb_k<<<2048 * 512 / 4 / 256, 256, 0, stream>>>(attn_W, W_hh, Wcomb);
  build_wenc_k<<<512 * 1024 / 4 / 256, 256, 0, stream>>>(attn_W, Wenc);
  build_wxw_k<<<1536 * 384 / 256, 256, 0, stream>>>(W_ih, Wx, Ww);
  hcast_k<<<64, 256, 0, stream>>>(hidden, hbf_step);
  enc_cast_k<<<B_ * S_ * 1024 / 4 / 256, 256, 0, stream>>>(enc, enc_bf);
  xgather_k<<<1984, 256, 0, stream>>>(trg, embed, Abf);

  // enc_proj_bf[8192,512] = enc_bf @ Wenc^T + attn_b (bf16 out)
  big_gemm_k<1><<<dim3(64, 4), 256, 0, stream>>>(enc_bf, 1024, Wenc, attn_b,
                                                 encp_bf, B_ * S_, 512, 1024);
  // gix_bf[1984,1536] = x @ Wx^T + b_ih (bf16 out)
  big_gemm_k<1><<<dim3(16, 12), 256, 0, stream>>>(Abf + 1536, 2048, Wx, b_ih,
                                                  gix_bf, 1984, 1536, 512);

  // recurrence + overlapped logits, one persistent launch
  fused_k<<<256, 512, 0, stream>>>(h, hbf_step, hgh_step, Wcomb, encp_bf, enc_bf,
                                   vv, srt, Ww, gix_bf, b_hh, Abf, outW_bf, out_b,
                                   out, gpart, syncb);
}

// Round 19
// 1408.637 us; speedup vs baseline: 1.0398x; 1.0398x over previous
//
#include <hip/hip_runtime.h>

typedef __attribute__((ext_vector_type(4))) float f32x4;
typedef __attribute__((ext_vector_type(2))) float f32x2;
typedef __attribute__((ext_vector_type(8))) short s16x8;
typedef __attribute__((ext_vector_type(4))) short s16x4;

#define B_ 64
#define S_ 128
#define T_ 32
#define H_ 512
#define V_ 32000
#define NTILES 2000  // 16 M-blocks(128 rows) * 125 col-tiles(256)

// sync layout: tile counter, 64 phase slots, aggregated step counter.
#define SY_TILE 32
#define SY_SLOT 64   // slots[0..63] at dwords 64..127
#define SY_DONE 192  // completed-steps counter (own line)

__device__ __forceinline__ unsigned short f2bf(float f) {
  union { float f; unsigned u; } x; x.f = f;
  unsigned r = x.u + 0x7FFFu + ((x.u >> 16) & 1u);
  return (unsigned short)(r >> 16);
}
__device__ __forceinline__ float bf2f(unsigned short u) {
  union { unsigned u; float f; } x; x.u = ((unsigned)u) << 16; return x.f;
}
__device__ __forceinline__ float fast_tanh(float x) {
  float e = __expf(2.0f * x);
  return 1.0f - 2.0f / (e + 1.0f);
}
__device__ __forceinline__ float fast_sig(float x) {
  return 1.0f / (1.0f + __expf(-x));
}
__device__ __forceinline__ void gload16(const void* g, void* l) {
  __builtin_amdgcn_global_load_lds(
      (const __attribute__((address_space(1))) void*)g,
      (__attribute__((address_space(3))) void*)l, 16, 0, 0);
}
__device__ __forceinline__ void gload16nt(const void* g, void* l) {
  __builtin_amdgcn_global_load_lds(
      (const __attribute__((address_space(1))) void*)g,
      (__attribute__((address_space(3))) void*)l, 16, 0, 2);
}

// coherent dword ops (bypass L1/L2, write-through) — no fences anywhere.
__device__ __forceinline__ unsigned ald(const unsigned* p) {
  return __hip_atomic_load(p, __ATOMIC_RELAXED, __HIP_MEMORY_SCOPE_AGENT);
}
__device__ __forceinline__ void ast(unsigned* p, unsigned v) {
  __hip_atomic_store(p, v, __ATOMIC_RELAXED, __HIP_MEMORY_SCOPE_AGENT);
}
__device__ __forceinline__ void astf(float* p, float v) {
  union { unsigned u; float f; } x; x.f = v; ast((unsigned*)p, x.u);
}

// Slot barrier (R12-proven): RELAXED arrival store (release emits buffer_wbl2,
// ~2.5µs/barrier); __syncthreads drains vmcnt first; data is write-through.
__device__ __forceinline__ void phase_sync(unsigned* sync, int bid,
                                           unsigned st_ph, int nmask,
                                           unsigned wt_ph) {
  __syncthreads();
  if (threadIdx.x == 0)
    __hip_atomic_store(&sync[SY_SLOT + bid], st_ph, __ATOMIC_RELAXED,
                       __HIP_MEMORY_SCOPE_AGENT);
  if (threadIdx.x < 64) {
    const unsigned* p = &sync[SY_SLOT + (threadIdx.x & nmask)];
    while (ald(p) < wt_ph) __builtin_amdgcn_s_sleep(1);
  }
  __syncthreads();
}

// ---------------------------------------------------------------------------
// Prep GEMM: C[Mv,N] = A[.,K]bf16(lda) @ W[N,K]bf16^T + bias; 128x128, BK=32.
// ---------------------------------------------------------------------------
template <int OUTBF>
__global__ __launch_bounds__(256) void big_gemm_k(
    const unsigned short* __restrict__ A, int lda,
    const unsigned short* __restrict__ W, const float* __restrict__ bias,
    void* __restrict__ Cv, int Mv, int N, int K) {
  __shared__ unsigned short As[128 * 32];
  __shared__ unsigned short Bs[128 * 32];
  const int t = threadIdx.x;
  const int wave = t >> 6, lane = t & 63;
  const int m0 = blockIdx.x * 128, n0 = blockIdx.y * 128;
  const int wm = (wave & 1) * 64, wn = (wave >> 1) * 64;
  const int fr = lane & 15, fq = lane >> 4;

  f32x4 acc[4][4];
#pragma unroll
  for (int i = 0; i < 4; ++i)
#pragma unroll
    for (int j = 0; j < 4; ++j) acc[i][j] = (f32x4){0.f, 0.f, 0.f, 0.f};

  const int g = (((lane & 3) ^ ((lane >> 3) & 3))) * 8;
  const size_t a_g0 = (size_t)(m0 + wave * 32 + (lane >> 2)) * lda + g;
  const size_t b_g0 = (size_t)(n0 + wave * 32 + (lane >> 2)) * K + g;
  unsigned short* As_w = As + wave * 1024;
  unsigned short* Bs_w = Bs + wave * 1024;
  const int sl = (fq ^ ((fr >> 1) & 3)) * 8;

  for (int kk = 0; kk < K; kk += 32) {
    gload16(A + a_g0 + kk, As_w);
    gload16(A + a_g0 + (size_t)16 * lda + kk, As_w + 512);
    gload16(W + b_g0 + kk, Bs_w);
    gload16(W + b_g0 + (size_t)16 * K + kk, Bs_w + 512);
    __syncthreads();
    s16x8 af[4], bfr[4];
#pragma unroll
    for (int f = 0; f < 4; ++f) {
      af[f] = *(const s16x8*)(As + (wm + f * 16 + fr) * 32 + sl);
      bfr[f] = *(const s16x8*)(Bs + (wn + f * 16 + fr) * 32 + sl);
    }
#pragma unroll
    for (int fm = 0; fm < 4; ++fm)
#pragma unroll
      for (int fn = 0; fn < 4; ++fn)
        acc[fm][fn] = __builtin_amdgcn_mfma_f32_16x16x32_bf16(af[fm], bfr[fn],
                                                              acc[fm][fn], 0, 0, 0);
    __syncthreads();
  }

#pragma unroll
  for (int fn = 0; fn < 4; ++fn) {
    int col = n0 + wn + fn * 16 + fr;
    float bv = bias[col];
#pragma unroll
    for (int fm = 0; fm < 4; ++fm) {
      int rb = m0 + wm + fm * 16 + fq * 4;
#pragma unroll
      for (int i = 0; i < 4; ++i) {
        int r = rb + i;
        if (r < Mv) {
          if (OUTBF)
            ((unsigned short*)Cv)[(size_t)r * N + col] = f2bf(acc[fm][fn][i] + bv);
          else
            ((float*)Cv)[(size_t)r * N + col] = acc[fm][fn][i] + bv;
        }
      }
    }
  }
}

// ---------------------------------------------------------------------------
// Fused persistent kernel: 256 blocks x 512 threads (1 block/CU). R13 body
// with FIXED LDS aliasing: Wp1 owns 32256..65536 exclusively; gsm/sc alias
// the A0/A1 staging region (dead when gsm/sc are live).
// Block 0 publishes SY_DONE=step+1 after each step's final barrier.
// Workers: logits tiles; gate = single-lane poll of SY_DONE.
// ---------------------------------------------------------------------------
__global__ __launch_bounds__(512) void fused_k(
    float* __restrict__ h, unsigned short* __restrict__ hbf_step,
    float* __restrict__ hgh_step, const unsigned short* __restrict__ Wcomb,
    const unsigned short* __restrict__ encp_bf,
    const unsigned short* __restrict__ enc_bf, const float* __restrict__ v,
    const int* __restrict__ src_tok, const unsigned short* __restrict__ Ww,
    const unsigned short* __restrict__ gix, const float* __restrict__ b_hh,
    unsigned short* __restrict__ Abf, const unsigned short* __restrict__ outW,
    const float* __restrict__ out_b, float* __restrict__ out,
    unsigned* __restrict__ sync) {
  __shared__ __align__(16) char smem[65536];
  const int t = threadIdx.x;
  const int lane = t & 63, w = t >> 6;
  const int fr = lane & 15, fq = lane >> 4;

  if (blockIdx.x < 64) {
    // ================= producer =================
    unsigned short* A0 = (unsigned short*)smem;            // [64][72] 9216
    unsigned short* A1 = (unsigned short*)(smem + 9216);   // [64][72]
    unsigned short* W0 = (unsigned short*)(smem + 18432);  // [48][72] 6912
    unsigned short* W1 = (unsigned short*)(smem + 25344);  // [48][72]
    unsigned short* Wp1 = (unsigned short*)(smem + 32256); // [32][520] 33280 (exclusive)
    float* gsm = (float*)smem;                             // [64][48] alias A0/A1
    float* sc = (float*)(smem + 12288);                    // [132]  alias A1
    const int j = blockIdx.x;
    const int ar = t >> 3, ak = (t & 7) * 8;
    const int p1_n0 = j * 32;
    const int rowt_p1 = w & 3, colt_p1 = w >> 2;
    const int rowt = (w < 4) ? w : (w - 4);

    // persistent P1 weight slice: Wcomb rows p1_n0..+32, K=512 (cached)
#pragma unroll
    for (int c = 0; c < 4; ++c) {
      int id = t * 4 + c;
      int r = id >> 6, cc = id & 63;
      s16x8 wv = *(const s16x8*)(Wcomb + (size_t)(p1_n0 + r) * 512 + cc * 8);
      *(s16x8*)(Wp1 + r * 520 + cc * 8) = wv;
    }

    // persistent P3 weight chunks in registers (step-invariant)
    const int wgate = ar >> 4, wdr = ar & 15;
    const int d0 = j * 16;
    const unsigned short* wwrow =
        Ww + (size_t)(wgate * 512 + d0 + wdr) * 1024 + ak;
    s16x8 pwreg[16];
    if (j < 32 && t < 384) {
#pragma unroll
      for (int p = 0; p < 16; ++p) pwreg[p] = *(const s16x8*)(wwrow + p * 64);
    }
    __syncthreads();

    for (int step = 0; step < 31; ++step) {
      const unsigned short* hbfS = hbf_step + (size_t)step * 64 * 512;
      unsigned short* hbfS1 = hbf_step + (size_t)(step + 1) * 64 * 512;
      float* hghS = hgh_step + (size_t)step * 64 * 2048;
      const unsigned ph = 3u * step;

      // ---------------- P1: hghS = hbfS @ Wcomb^T (dbuf, 1 sync/iter) ------
      {
        s16x8 pa[8];
#pragma unroll
        for (int p = 0; p < 8; ++p)
          pa[p] = *(const s16x8*)(hbfS + ar * 512 + p * 64 + ak);
        *(s16x8*)(A0 + ar * 72 + ak) = pa[0];
        __syncthreads();
        f32x4 acc = {0.f, 0.f, 0.f, 0.f};
#pragma unroll
        for (int it = 0; it < 8; ++it) {
          unsigned short* bufR = (it & 1) ? A1 : A0;
          unsigned short* bufW = (it & 1) ? A0 : A1;
          s16x8 a0 = *(const s16x8*)(bufR + (rowt_p1 * 16 + fr) * 72 + fq * 8);
          s16x8 a1 =
              *(const s16x8*)(bufR + (rowt_p1 * 16 + fr) * 72 + 32 + fq * 8);
          if (it < 7) *(s16x8*)(bufW + ar * 72 + ak) = pa[it + 1];
          s16x8 b0 =
              *(const s16x8*)(Wp1 + (colt_p1 * 16 + fr) * 520 + it * 64 + fq * 8);
          s16x8 b1 = *(const s16x8*)(Wp1 + (colt_p1 * 16 + fr) * 520 + it * 64 +
                                     32 + fq * 8);
          acc = __builtin_amdgcn_mfma_f32_16x16x32_bf16(a0, b0, acc, 0, 0, 0);
          acc = __builtin_amdgcn_mfma_f32_16x16x32_bf16(a1, b1, acc, 0, 0, 0);
          __syncthreads();
        }
        int col = p1_n0 + colt_p1 * 16 + fr;
#pragma unroll
        for (int i = 0; i < 4; ++i)
          astf(&hghS[(rowt_p1 * 16 + fq * 4 + i) * 2048 + col], acc[i]);
      }
      phase_sync(sync, j, ph + 1, 15, ph + 1);  // wait hproj (blocks 0..15)

      // ---------------- P2: attention for b = j ----------------
      {
        const int b = j;
        const float* hp = hghS + (size_t)b * 2048;
        float vh[8], hh[8];
        {
          f32x4 v0 = *(const f32x4*)(v + lane * 8);
          f32x4 v1 = *(const f32x4*)(v + lane * 8 + 4);
          f32x4 h0 = *(const f32x4*)(hp + lane * 8);
          f32x4 h1 = *(const f32x4*)(hp + lane * 8 + 4);
#pragma unroll
          for (int q = 0; q < 4; ++q) {
            vh[q] = v0[q]; vh[4 + q] = v1[q];
            hh[q] = h0[q]; hh[4 + q] = h1[q];
          }
        }
        for (int s = w * 16; s < w * 16 + 16; ++s) {
          s16x8 e =
              *(const s16x8*)(encp_bf + (size_t)(b * 128 + s) * 512 + lane * 8);
          float p = 0.f;
#pragma unroll
          for (int q = 0; q < 8; ++q)
            p += vh[q] * fast_tanh(hh[q] + bf2f((unsigned short)e[q]));
          for (int m = 32; m; m >>= 1) p += __shfl_xor(p, m);
          if (lane == 0)
            sc[s] = (src_tok[b * 128 + s] != 0) ? p : -__builtin_inff();
        }
        __syncthreads();
        if (t < 64) {
          float a0 = sc[t], a1 = sc[t + 64];
          float mx = fmaxf(a0, a1);
          for (int m = 32; m; m >>= 1) mx = fmaxf(mx, __shfl_xor(mx, m));
          float e0 = __expf(a0 - mx), e1 = __expf(a1 - mx);
          float ssum = e0 + e1;
          for (int m = 32; m; m >>= 1) ssum += __shfl_xor(ssum, m);
          float inv = 1.0f / ssum;
          sc[t] = e0 * inv;
          sc[t + 64] = e1 * inv;
        }
        __syncthreads();
        const int d = t * 2;
        float w0 = 0.f, w1 = 0.f;
#pragma unroll 16
        for (int s = 0; s < 128; ++s) {
          float a = sc[s];
          unsigned u = *(const unsigned*)(enc_bf + (size_t)(b * 128 + s) * 1024 + d);
          union { unsigned u; float f; } lo, hi;
          lo.u = u << 16; hi.u = u & 0xffff0000u;
          w0 += a * lo.f; w1 += a * hi.f;
        }
        unsigned pk = ((unsigned)f2bf(w1) << 16) | (unsigned)f2bf(w0);
        ast((unsigned*)(Abf + (size_t)(step * 64 + b) * 2048 + 512 + d), pk);
      }
      phase_sync(sync, j, ph + 2, 63, ph + 2);  // wait all: weighted + gates

      // ---------------- P3 + GRU (blocks j < 32): dbuf + reg-W -------------
      if (j < 32) {
        const int r0 = step * 64;
        const unsigned short* abrow = Abf + (size_t)(r0 + ar) * 2048 + 512 + ak;
        s16x8 pa[16];
#pragma unroll
        for (int p = 0; p < 16; ++p) pa[p] = *(const s16x8*)(abrow + p * 64);
        *(s16x8*)(A0 + ar * 72 + ak) = pa[0];
        if (t < 384) *(s16x8*)(W0 + ar * 72 + ak) = pwreg[0];
        __syncthreads();
        f32x4 acc0 = {0.f, 0.f, 0.f, 0.f}, acc1 = {0.f, 0.f, 0.f, 0.f};
#pragma unroll
        for (int it = 0; it < 16; ++it) {
          unsigned short* aR = (it & 1) ? A1 : A0;
          unsigned short* wR = (it & 1) ? W1 : W0;
          unsigned short* aW = (it & 1) ? A0 : A1;
          unsigned short* wW = (it & 1) ? W0 : W1;
          s16x8 a0 = *(const s16x8*)(aR + (rowt * 16 + fr) * 72 + fq * 8);
          s16x8 a1 = *(const s16x8*)(aR + (rowt * 16 + fr) * 72 + 32 + fq * 8);
          if (it < 15) {
            *(s16x8*)(aW + ar * 72 + ak) = pa[it + 1];
            if (t < 384) *(s16x8*)(wW + ar * 72 + ak) = pwreg[it + 1];
          }
          if (w < 4) {
            s16x8 b0 = *(const s16x8*)(wR + fr * 72 + fq * 8);
            s16x8 b1 = *(const s16x8*)(wR + fr * 72 + 32 + fq * 8);
            s16x8 c0 = *(const s16x8*)(wR + (32 + fr) * 72 + fq * 8);
            s16x8 c1 = *(const s16x8*)(wR + (32 + fr) * 72 + 32 + fq * 8);
            acc0 = __builtin_amdgcn_mfma_f32_16x16x32_bf16(a0, b0, acc0, 0, 0, 0);
            acc0 = __builtin_amdgcn_mfma_f32_16x16x32_bf16(a1, b1, acc0, 0, 0, 0);
            acc1 = __builtin_amdgcn_mfma_f32_16x16x32_bf16(a0, c0, acc1, 0, 0, 0);
            acc1 = __builtin_amdgcn_mfma_f32_16x16x32_bf16(a1, c1, acc1, 0, 0, 0);
          } else {
            s16x8 b0 = *(const s16x8*)(wR + (16 + fr) * 72 + fq * 8);
            s16x8 b1 = *(const s16x8*)(wR + (16 + fr) * 72 + 32 + fq * 8);
            acc0 = __builtin_amdgcn_mfma_f32_16x16x32_bf16(a0, b0, acc0, 0, 0, 0);
            acc0 = __builtin_amdgcn_mfma_f32_16x16x32_bf16(a1, b1, acc0, 0, 0, 0);
          }
          __syncthreads();
        }
        {
          const int colt0 = (w < 4) ? 0 : 1;
#pragma unroll
          for (int i = 0; i < 4; ++i) {
            int row = rowt * 16 + fq * 4 + i;
            gsm[row * 48 + colt0 * 16 + fr] =
                acc0[i] +
                bf2f(gix[(size_t)(r0 + row) * 1536 + colt0 * 512 + d0 + fr]);
          }
          if (w < 4) {
#pragma unroll
            for (int i = 0; i < 4; ++i) {
              int row = rowt * 16 + fq * 4 + i;
              gsm[row * 48 + 32 + fr] =
                  acc1[i] + bf2f(gix[(size_t)(r0 + row) * 1536 + 1024 + d0 + fr]);
            }
          }
        }
        __syncthreads();
        {
          int e = t * 2;
          int b = e >> 4, dd = e & 15, d = d0 + dd;
          float hv2[2];
          unsigned short hb2[2];
#pragma unroll
          for (int k = 0; k < 2; ++k) {
            float ir = gsm[b * 48 + dd + k];
            float iz = gsm[b * 48 + 16 + dd + k];
            float inn = gsm[b * 48 + 32 + dd + k];
            float hr = hghS[b * 2048 + 512 + d + k] + b_hh[d + k];
            float hz = hghS[b * 2048 + 1024 + d + k] + b_hh[512 + d + k];
            float hn = hghS[b * 2048 + 1536 + d + k] + b_hh[1024 + d + k];
            float r = fast_sig(ir + hr);
            float z = fast_sig(iz + hz);
            float n = fast_tanh(inn + r * hn);
            hv2[k] = (1.0f - z) * n + z * h[b * 512 + d + k];
            hb2[k] = f2bf(hv2[k]);
          }
          h[b * 512 + d] = hv2[0];  // producer-block-local across steps
          h[b * 512 + d + 1] = hv2[1];
          unsigned pk = ((unsigned)hb2[1] << 16) | (unsigned)hb2[0];
          ast((unsigned*)(hbfS1 + b * 512 + d), pk);
          ast((unsigned*)(Abf + (size_t)(r0 + b) * 2048 + d), pk);
        }
      }
      phase_sync(sync, j, ph + 3, 31, ph + 3);  // wait hbf writers (0..31)
      // Block 0 has now observed slots 0..31 >= ph+3 -> step complete.
      if (j == 0 && t == 0) ast(&sync[SY_DONE], (unsigned)(step + 1));
    }
  }

  // ================= worker (all blocks; producers join when done) ==========
  unsigned short* As2 = (unsigned short*)smem;            // [128][64] swizzled
  unsigned short* Bs2 = (unsigned short*)(smem + 16384);  // [256][64] swizzled
  unsigned* shp = (unsigned*)(smem + 65532);              // sh_idx (alias)
  const int wr = (w >> 2) * 64, wc = (w & 3) * 64;

  int rowA[2], cgA[2], rowB[4], cgB[4];
#pragma unroll
  for (int c = 0; c < 2; ++c) {
    int id = (w * 2 + c) * 64 + lane;
    rowA[c] = id >> 3;
    cgA[c] = ((id & 7) - rowA[c]) & 7;
  }
#pragma unroll
  for (int c = 0; c < 4; ++c) {
    int id = (w * 4 + c) * 64 + lane;
    rowB[c] = id >> 3;
    cgB[c] = ((id & 7) - rowB[c]) & 7;
  }

  for (;;) {
    __syncthreads();
    if (t == 0)
      *shp = __hip_atomic_fetch_add(&sync[SY_TILE], 1u, __ATOMIC_RELAXED,
                                    __HIP_MEMORY_SCOPE_AGENT);
    __syncthreads();
    unsigned idx = *shp;
    if (idx >= NTILES) break;
    int mb = idx / 125;
    int nt = idx - mb * 125;
    int gate = mb * 2 + 1;
    if (gate > 30) gate = 30;
    unsigned need = (unsigned)gate + 1u;  // steps completed
    if (t == 0) {
      while (ald(&sync[SY_DONE]) < need) __builtin_amdgcn_s_sleep(32);
    }
    __syncthreads();

    const int m0 = mb * 128, n0 = nt * 256;
    f32x4 acc[4][4];
#pragma unroll
    for (int i = 0; i < 4; ++i)
#pragma unroll
      for (int jj = 0; jj < 4; ++jj) acc[i][jj] = (f32x4){0.f, 0.f, 0.f, 0.f};

    for (int kk = 0; kk < 2048; kk += 64) {
#pragma unroll
      for (int c = 0; c < 2; ++c)
        gload16(Abf + (size_t)(m0 + rowA[c]) * 2048 + kk + cgA[c] * 8,
                As2 + (w * 2 + c) * 512);
#pragma unroll
      for (int c = 0; c < 4; ++c)
        gload16nt(outW + (size_t)(n0 + rowB[c]) * 2048 + kk + cgB[c] * 8,
                  Bs2 + (w * 4 + c) * 512);
      __syncthreads();
#pragma unroll
      for (int kh = 0; kh < 2; ++kh) {
        int cg = kh * 4 + fq;
        s16x8 af[4], bf_[4];
#pragma unroll
        for (int i = 0; i < 4; ++i) {
          int rr = wr + i * 16 + fr;
          af[i] = *(const s16x8*)(As2 + rr * 64 + (((cg + rr) & 7) * 8));
        }
#pragma unroll
        for (int jj = 0; jj < 4; ++jj) {
          int rr = wc + jj * 16 + fr;
          bf_[jj] = *(const s16x8*)(Bs2 + rr * 64 + (((cg + rr) & 7) * 8));
        }
#pragma unroll
        for (int i = 0; i < 4; ++i)
#pragma unroll
          for (int jj = 0; jj < 4; ++jj)
            acc[i][jj] = __builtin_amdgcn_mfma_f32_16x16x32_bf16(
                af[i], bf_[jj], acc[i][jj], 0, 0, 0);
      }
      __syncthreads();
    }

#pragma unroll
    for (int jj = 0; jj < 4; ++jj) {
      int col = n0 + wc + jj * 16 + fr;
      float bv = out_b[col];
#pragma unroll
      for (int i = 0; i < 4; ++i) {
        int rb = m0 + wr + i * 16 + fq * 4;
#pragma unroll
        for (int ii = 0; ii < 4; ++ii) {
          int r = rb + ii;
          if (r < 1984) out[(size_t)(r + 64) * V_ + col] = acc[i][jj][ii] + bv;
        }
      }
    }
  }
}

// ---------------------------------------------------------------------------
// Prep kernels
// ---------------------------------------------------------------------------
__global__ __launch_bounds__(256) void cast_bf16_k(const float* __restrict__ src,
                                                   unsigned short* __restrict__ dst,
                                                   int n4) {
  int i = blockIdx.x * 256 + threadIdx.x;
  if (i >= n4) return;
  f32x4 f = *(const f32x4*)(src + (size_t)i * 4);
  s16x4 o;
#pragma unroll
  for (int q = 0; q < 4; ++q) o[q] = (short)f2bf(f[q]);
  *(s16x4*)(dst + (size_t)i * 4) = o;
}

__global__ __launch_bounds__(256) void enc_cast_k(const float* __restrict__ enc,
                                                  unsigned short* __restrict__ dst) {
  int i = blockIdx.x * 256 + threadIdx.x;
  int n = i * 4;
  int row = n >> 10, d = n & 1023;
  int s = row & (S_ - 1), b = row >> 7;
  f32x4 f = *(const f32x4*)(enc + ((size_t)s * B_ + b) * 1024 + d);
  s16x4 o;
#pragma unroll
  for (int q = 0; q < 4; ++q) o[q] = (short)f2bf(f[q]);
  *(s16x4*)(dst + (size_t)row * 1024 + d) = o;
}

__global__ __launch_bounds__(256) void build_wcomb_k(const float* __restrict__ aW,
                                                     const float* __restrict__ whh,
                                                     unsigned short* __restrict__ dst) {
  int idx = (blockIdx.x * 256 + threadIdx.x) * 4;
  int n = idx >> 9, k = idx & 511;
  const float* src = (n < 512) ? (aW + (size_t)n * 1536 + k)
                               : (whh + (size_t)(n - 512) * 512 + k);
  f32x4 f = *(const f32x4*)src;
  s16x4 o;
#pragma unroll
  for (int q = 0; q < 4; ++q) o[q] = (short)f2bf(f[q]);
  *(s16x4*)(dst + idx) = o;
}

__global__ __launch_bounds__(256) void build_wenc_k(const float* __restrict__ aW,
                                                    unsigned short* __restrict__ dst) {
  int idx = (blockIdx.x * 256 + threadIdx.x) * 4;
  int n = idx >> 10, k = idx & 1023;
  f32x4 f = *(const f32x4*)(aW + (size_t)n * 1536 + 512 + k);
  s16x4 o;
#pragma unroll
  for (int q = 0; q < 4; ++q) o[q] = (short)f2bf(f[q]);
  *(s16x4*)(dst + idx) = o;
}

__global__ __launch_bounds__(256) void build_wxw_k(const float* __restrict__ wih,
                                                   unsigned short* __restrict__ wx,
                                                   unsigned short* __restrict__ ww) {
  int flat = blockIdx.x * 256 + threadIdx.x;  // over 1536*384
  int n = flat / 384, c4 = (flat % 384) * 4;
  f32x4 f = *(const f32x4*)(wih + (size_t)n * 1536 + c4);
  s16x4 o;
#pragma unroll
  for (int q = 0; q < 4; ++q) o[q] = (short)f2bf(f[q]);
  if (c4 < 512)
    *(s16x4*)(wx + (size_t)n * 512 + c4) = o;
  else
    *(s16x4*)(ww + (size_t)n * 1024 + (c4 - 512)) = o;
}

__global__ __launch_bounds__(256) void hcast_k(const float* __restrict__ hidden,
                                               unsigned short* __restrict__ hbf0) {
  int i = blockIdx.x * 256 + threadIdx.x;
  f32x2 f = *(const f32x2*)(hidden + (size_t)i * 2);
  unsigned pk = ((unsigned)f2bf(f[1]) << 16) | (unsigned)f2bf(f[0]);
  *(unsigned*)(hbf0 + (size_t)i * 2) = pk;
}

__global__ __launch_bounds__(256) void xgather_k(const int* __restrict__ trg,
                                                 const float* __restrict__ embed,
                                                 unsigned short* __restrict__ Abf) {
  int row = blockIdx.x;  // 0..1983
  int tt = row >> 6, b = row & 63;
  int tok = trg[b * T_ + tt];
  int d = threadIdx.x * 2;
  unsigned pk = 0;
  if (tok != 0) {
    f32x2 f = *(const f32x2*)(embed + (size_t)tok * H_ + d);
    pk = ((unsigned)f2bf(f[1]) << 16) | (unsigned)f2bf(f[0]);
  }
  *(unsigned*)(Abf + (size_t)row * 2048 + 1536 + d) = pk;
}

extern "C" void kernel_launch(void* const* d_in, const int* in_sizes, int n_in,
                              void* d_out, int out_size, void* d_ws, size_t ws_size,
                              hipStream_t stream) {
  const int* trg = (const int*)d_in[0];
  const int* srt = (const int*)d_in[1];
  const float* enc = (const float*)d_in[2];
  const float* hidden = (const float*)d_in[3];
  const float* embed = (const float*)d_in[4];
  const float* attn_W = (const float*)d_in[5];
  const float* attn_b = (const float*)d_in[6];
  const float* vv = (const float*)d_in[7];
  const float* W_ih = (const float*)d_in[8];
  const float* W_hh = (const float*)d_in[9];
  const float* b_ih = (const float*)d_in[10];
  const float* b_hh = (const float*)d_in[11];
  const float* out_W = (const float*)d_in[12];
  const float* out_b = (const float*)d_in[13];
  float* out = (float*)d_out;

  char* ws = (char*)d_ws;
  size_t off = 0;
  auto alloc = [&](size_t bytes) {
    size_t o = off;
    off += (bytes + 255) & ~(size_t)255;
    return ws + o;
  };

  unsigned short* outW_bf = (unsigned short*)alloc((size_t)V_ * 2048 * 2);
  unsigned short* Abf = (unsigned short*)alloc((size_t)2048 * 2048 * 2);
  unsigned short* enc_bf = (unsigned short*)alloc((size_t)B_ * S_ * 1024 * 2);
  unsigned short* encp_bf = (unsigned short*)alloc((size_t)B_ * S_ * 512 * 2);
  unsigned short* gix_bf = (unsigned short*)alloc((size_t)1984 * 1536 * 2);
  unsigned short* Wcomb = (unsigned short*)alloc((size_t)2048 * 512 * 2);
  unsigned short* Wenc = (unsigned short*)alloc((size_t)512 * 1024 * 2);
  unsigned short* Wx = (unsigned short*)alloc((size_t)1536 * 512 * 2);
  unsigned short* Ww = (unsigned short*)alloc((size_t)1536 * 1024 * 2);
  float* hgh_step = (float*)alloc((size_t)31 * B_ * 2048 * 4);  // 16.25 MB
  unsigned short* hbf_step = (unsigned short*)alloc((size_t)32 * B_ * H_ * 2);
  float* h = (float*)alloc((size_t)B_ * H_ * 4);
  unsigned* syncb = (unsigned*)alloc(8192);

  hipMemsetAsync(out, 0, (size_t)B_ * V_ * 4, stream);
  hipMemsetAsync(syncb, 0, 8192, stream);
  hipMemsetAsync(Abf + (size_t)1984 * 2048, 0, (size_t)64 * 2048 * 2, stream);
  hipMemcpyAsync(h, hidden, (size_t)B_ * H_ * 4, hipMemcpyDeviceToDevice, stream);

  cast_bf16_k<<<(V_ * 2048 / 4 + 255) / 256, 256, 0, stream>>>(out_W, outW_bf,
                                                               V_ * 2048 / 4);
  build_wcomb_k<<<2048 * 512 / 4 / 256, 256, 0, stream>>>(attn_W, W_hh, Wcomb);
  build_wenc_k<<<512 * 1024 / 4 / 256, 256, 0, stream>>>(attn_W, Wenc);
  build_wxw_k<<<1536 * 384 / 256, 256, 0, stream>>>(W_ih, Wx, Ww);
  hcast_k<<<64, 256, 0, stream>>>(hidden, hbf_step);
  enc_cast_k<<<B_ * S_ * 1024 / 4 / 256, 256, 0, stream>>>(enc, enc_bf);
  xgather_k<<<1984, 256, 0, stream>>>(trg, embed, Abf);

  // enc_proj_bf[8192,512] = enc_bf @ Wenc^T + attn_b (bf16 out)
  big_gemm_k<1><<<dim3(64, 4), 256, 0, stream>>>(enc_bf, 1024, Wenc, attn_b,
                                                 encp_bf, B_ * S_, 512, 1024);
  // gix_bf[1984,1536] = x @ Wx^T + b_ih (bf16 out)
  big_gemm_k<1><<<dim3(16, 12), 256, 0, stream>>>(Abf + 1536, 2048, Wx, b_ih,
                                                  gix_bf, 1984, 1536, 512);

  // recurrence + overlapped logits, one persistent launch
  fused_k<<<256, 512, 0, stream>>>(h, hbf_step, hgh_step, Wcomb, encp_bf, enc_bf,
                                   vv, srt, Ww, gix_bf, b_hh, Abf, outW_bf, out_b,
                                   out, syncb);
}